// Round 5
// baseline (820.540 us; speedup 1.0000x reference)
//
#include <hip/hip_runtime.h>

#define N_NODES 50000
#define N_EDGES 800000
#define NFEAT 128
#define DIM 32
#define HEADS 16
#define NGRAPH 64

// ============================ index decode (int32/int64 robust) ============================
// If the harness passes int64 data, every value < 2^31 so high words are 0.
// Detect by checking the tail region that is in-bounds for BOTH interpretations.

__device__ inline bool edges_are_i64(const int* raw) {
    int acc = 0;
#pragma unroll
    for (int i = 1; i < 16; i += 2) acc |= raw[2 * N_EDGES - 16 + i];
    return acc == 0;   // random dst values: odd words all-zero only if int64
}

__global__ __launch_bounds__(256) void decode_edges(const int* __restrict__ raw,
                                                    int* __restrict__ esrc,
                                                    int* __restrict__ edst) {
    const bool is64 = edges_are_i64(raw);
    int e = blockIdx.x * 256 + threadIdx.x;
    if (e < N_EDGES) {
        if (is64) { esrc[e] = raw[2 * e]; edst[e] = raw[2 * (N_EDGES + e)]; }
        else      { esrc[e] = raw[e];     edst[e] = raw[N_EDGES + e]; }
    }
}

__global__ __launch_bounds__(256) void decode_batch(const int* __restrict__ raw,
                                                    int* __restrict__ out) {
    int acc = 0;
#pragma unroll
    for (int i = 1; i < 16; i += 2) acc |= raw[N_NODES - 16 + i];
    const bool is64 = (acc == 0);  // tail of batch is ~63 (nonzero) if int32
    int b = blockIdx.x * 256 + threadIdx.x;
    if (b < N_NODES) {
        int v = is64 ? raw[2 * b] : raw[b];
        out[b] = v < 0 ? 0 : (v >= NGRAPH ? NGRAPH - 1 : v);  // defensive clamp
    }
}

// ============================ CSR build ============================
__global__ __launch_bounds__(256) void init_kernel(int* __restrict__ deg, float* __restrict__ gpool) {
    int i = blockIdx.x * 256 + threadIdx.x;
    if (i < N_NODES) deg[i] = 1;          // self-loop for GAT
    if (i < NGRAPH * DIM) gpool[i] = 0.f;
}

__device__ inline int clampN(int v) {
    return v < 0 ? 0 : (v >= N_NODES ? N_NODES - 1 : v);
}

__global__ __launch_bounds__(256) void hist_kernel(const int* __restrict__ edst, int* __restrict__ deg) {
    int e = blockIdx.x * 256 + threadIdx.x;
    if (e < N_EDGES) atomicAdd(&deg[clampN(edst[e])], 1);
}

__global__ __launch_bounds__(1024) void scan_kernel(const int* __restrict__ deg,
                                                    int* __restrict__ off, int* __restrict__ cur) {
    __shared__ int part[1024];
    const int t = threadIdx.x;
    const int CH = (N_NODES + 1023) / 1024;  // 49
    int b0 = t * CH, b1 = b0 + CH;
    if (b0 > N_NODES) b0 = N_NODES;
    if (b1 > N_NODES) b1 = N_NODES;
    int s = 0;
    for (int i = b0; i < b1; ++i) s += deg[i];
    part[t] = s;
    __syncthreads();
    for (int ofs = 1; ofs < 1024; ofs <<= 1) {
        int v = part[t];
        int u = (t >= ofs) ? part[t - ofs] : 0;
        __syncthreads();
        part[t] = v + u;
        __syncthreads();
    }
    int run = (t > 0) ? part[t - 1] : 0;
    for (int i = b0; i < b1; ++i) { off[i] = run; cur[i] = run; run += deg[i]; }
    if (t == 1023) off[N_NODES] = part[1023];
}

__global__ __launch_bounds__(256) void place_kernel(const int* __restrict__ esrc,
                                                    const int* __restrict__ edst,
                                                    int* __restrict__ cur, int* __restrict__ nbr) {
    int idx = blockIdx.x * 256 + threadIdx.x;
    if (idx >= N_EDGES + N_NODES) return;
    int d, v;
    if (idx < N_EDGES) { d = clampN(edst[idx]); v = clampN(esrc[idx]); }
    else { d = idx - N_EDGES; v = d; }
    int p = atomicAdd(&cur[d], 1);
    nbr[p] = v;
}

// ============================ stage-1 node GEMM: xrb = [x@W1_rel | x@W1_root + b1] ============================
__global__ __launch_bounds__(256) void node_linear2(const float* __restrict__ x,
                                                    const float* __restrict__ Wa,
                                                    const float* __restrict__ Wb,
                                                    const float* __restrict__ bias_b,
                                                    float* __restrict__ xrb, int n) {
    constexpr int KC = 128;
    constexpr int NB = 8;
    __shared__ float sWt[2][32][KC + 4];
    __shared__ float sX[NB][KC];
    const int t = threadIdx.x;
    const int o = t & 63;
    const int mat = o >> 5;
    const int c = o & 31;
    const int sub = t >> 6;
    const int base = blockIdx.x * NB;

    // weights (transposed)
    for (int i = t; i < 2 * KC * 32; i += 256) {
        int m = i >= KC * 32;
        int j = i - m * KC * 32;
        int kk = j >> 5, cc = j & 31;
        sWt[m][cc][kk] = (m ? Wb : Wa)[kk * 32 + cc];
    }
    for (int i = t; i < NB * KC; i += 256) {
        int r = i >> 7, kk = i & (KC - 1);
        int node = base + r;
        sX[r][kk] = (node < n) ? x[(size_t)node * KC + kk] : 0.f;
    }
    __syncthreads();
    float acc[2] = {0.f, 0.f};
#pragma unroll 4
    for (int kv = 0; kv < KC / 4; ++kv) {
        const float4 w = *(const float4*)&sWt[mat][c][kv * 4];
#pragma unroll
        for (int s = 0; s < 2; ++s) {
            const float4 xv = *(const float4*)&sX[sub + s * 4][kv * 4];
            acc[s] += w.x * xv.x + w.y * xv.y + w.z * xv.z + w.w * xv.w;
        }
    }
    const float bb = (mat == 1) ? bias_b[c] : 0.f;
#pragma unroll
    for (int s = 0; s < 2; ++s) {
        int node = base + sub + s * 4;
        if (node < n) xrb[(size_t)node * 64 + mat * 32 + c] = acc[s] + bb;
    }
}

// ============================ GraphConv gather: out = relu(sum_nbr xrb[s][c] - self + root) ============================
__global__ __launch_bounds__(256) void graphconv_gather(const float* __restrict__ xrb,
                                                        const int* __restrict__ off,
                                                        const int* __restrict__ nbr,
                                                        float* __restrict__ out) {
    int d = blockIdx.x * 4 + (threadIdx.x >> 6);
    if (d >= N_NODES) return;
    const int l = threadIdx.x & 63;
    const int c = l & 31, half = l >> 5;
    const int j0 = off[d], j1 = off[d + 1];
    float acc = 0.f;
    for (int j = j0 + half; j < j1; j += 2) acc += xrb[(size_t)nbr[j] * 64 + c];
    acc += __shfl_xor(acc, 32);
    // remove the injected self-loop, add root path (carries bias)
    acc += xrb[(size_t)d * 64 + 32 + c] - xrb[(size_t)d * 64 + c];
    if (half == 0) out[(size_t)d * 32 + c] = acc > 0.f ? acc : 0.f;
}

// ============================ GAT attention composite vectors ============================
// attc[sd][k][hd] = sum_c Wg[k][hd*32+c] * att[sd][hd][c]
__global__ __launch_bounds__(1024) void attc_kernel(const float* __restrict__ Wg,
                                                    const float* __restrict__ attS,
                                                    const float* __restrict__ attD,
                                                    float* __restrict__ attc) {
    const int t = threadIdx.x;
    const int sd = t >> 9, k = (t >> 4) & 31, hd = t & 15;
    const float* att = sd ? attD : attS;
    float acc = 0.f;
#pragma unroll
    for (int c = 0; c < 32; ++c) acc += Wg[k * 512 + hd * 32 + c] * att[hd * 32 + c];
    attc[t] = acc;
}

// asrc/adst[n][hd] = sum_k h1[n][k] * attc[sd][k][hd]
__global__ __launch_bounds__(256) void gat_att(const float* __restrict__ h1,
                                               const float* __restrict__ attc,
                                               float* __restrict__ asrc,
                                               float* __restrict__ adst) {
    __shared__ float sh1[8][32];
    __shared__ float sattc[1024];
    const int t = threadIdx.x;
    for (int i = t; i < 1024; i += 256) sattc[i] = attc[i];
    {
        int n0 = t >> 5, k = t & 31;
        sh1[n0][k] = h1[(size_t)(blockIdx.x * 8 + n0) * 32 + k];
    }
    __syncthreads();
    const int nl = t >> 5, hd = (t >> 1) & 15, sd = t & 1;
    float acc = 0.f;
#pragma unroll
    for (int k = 0; k < 32; ++k) acc += sh1[nl][k] * sattc[sd * 512 + k * 16 + hd];
    (sd ? adst : asrc)[(size_t)(blockIdx.x * 8 + nl) * 16 + hd] = acc;
}

// ============================ GAT mega kernel ============================
// Per wave: dst node gather + in-register online softmax (per-head 32-dim aggregate),
// then block-wide: @Wg + bg + relu (h2 in LDS), then @[W5_rel|W5_root] + b5 -> xrb.
__global__ __launch_bounds__(512) void gat_mega(const float* __restrict__ h1,
                                                const float* __restrict__ asrc,
                                                const float* __restrict__ adst,
                                                const int* __restrict__ off,
                                                const int* __restrict__ nbr,
                                                const float* __restrict__ Wg,
                                                const float* __restrict__ bg,
                                                const float* __restrict__ W5_rel,
                                                const float* __restrict__ W5_root,
                                                const float* __restrict__ b5,
                                                float* __restrict__ xrb) {
    __shared__ float sh_agg[8][512];
    __shared__ float sh_h2[8][512];
    __shared__ float spart[8][8][64];
    const int t = threadIdx.x;
    const int w = t >> 6, l = t & 63;
    const int d = blockIdx.x * 8 + w;

    // ---- gather + online softmax (per wave) ----
    {
        const int hd = l & 15;
        const int kb = (l >> 4) << 3;
        const float adst_v = adst[(size_t)d * 16 + hd];
        const int j0 = off[d], j1 = off[d + 1];
        float m = -1e30f;
        for (int j = j0; j < j1; ++j) {
            int s = nbr[j];
            float e = asrc[(size_t)s * 16 + hd] + adst_v;
            e = e < 0.f ? 0.2f * e : e;
            m = fmaxf(m, e);
        }
        float den = 0.f;
        float4 acca = {0.f, 0.f, 0.f, 0.f}, accb = {0.f, 0.f, 0.f, 0.f};
        for (int j = j0; j < j1; ++j) {
            int s = nbr[j];
            float e = asrc[(size_t)s * 16 + hd] + adst_v;
            e = e < 0.f ? 0.2f * e : e;
            float ex = expf(e - m);
            den += ex;
            const float4 ha = *(const float4*)&h1[(size_t)s * 32 + kb];
            const float4 hb = *(const float4*)&h1[(size_t)s * 32 + kb + 4];
            acca.x += ex * ha.x; acca.y += ex * ha.y; acca.z += ex * ha.z; acca.w += ex * ha.w;
            accb.x += ex * hb.x; accb.y += ex * hb.y; accb.z += ex * hb.z; accb.w += ex * hb.w;
        }
        const float r = 1.f / (den + 1e-16f);
        acca.x *= r; acca.y *= r; acca.z *= r; acca.w *= r;
        accb.x *= r; accb.y *= r; accb.z *= r; accb.w *= r;
        *(float4*)&sh_agg[w][hd * 32 + kb] = acca;
        *(float4*)&sh_agg[w][hd * 32 + kb + 4] = accb;
    }
    __syncthreads();

    // ---- phase1: h2[nl][t] = relu(sum_k sh_agg[nl][hd*32+k] * Wg[k][t] + bg[t]) ----
    {
        const int hh = (t >> 5) << 5;
        float acc[8] = {0.f, 0.f, 0.f, 0.f, 0.f, 0.f, 0.f, 0.f};
        for (int k = 0; k < 32; ++k) {
            const float wv = Wg[k * 512 + t];
#pragma unroll
            for (int nl = 0; nl < 8; ++nl) acc[nl] += sh_agg[nl][hh + k] * wv;
        }
        const float bgv = bg[t];
#pragma unroll
        for (int nl = 0; nl < 8; ++nl) {
            float v = acc[nl] + bgv;
            sh_h2[nl][t] = v > 0.f ? v : 0.f;
        }
    }
    __syncthreads();

    // ---- phase2: wave w covers cols [w*64, w*64+64); lane l = output index ----
    {
        const float* wp = (l < 32) ? (W5_rel + l) : (W5_root + (l - 32));
        float acc[8] = {0.f, 0.f, 0.f, 0.f, 0.f, 0.f, 0.f, 0.f};
        const int c0 = w * 64;
        for (int cc = 0; cc < 64; ++cc) {
            const int col = c0 + cc;
            const float wv = wp[(size_t)col * 32];
#pragma unroll
            for (int nl = 0; nl < 8; ++nl) acc[nl] += sh_h2[nl][col] * wv;
        }
#pragma unroll
        for (int nl = 0; nl < 8; ++nl) spart[w][nl][l] = acc[nl];
    }
    __syncthreads();

    // ---- reduce partials; wave w finalizes node nl = w ----
    {
        float acc = (l >= 32) ? b5[l - 32] : 0.f;
#pragma unroll
        for (int ww = 0; ww < 8; ++ww) acc += spart[ww][w][l];
        xrb[(size_t)(blockIdx.x * 8 + w) * 64 + l] = acc;
    }
}

// ============================ pool + head ============================
__global__ __launch_bounds__(256) void pool_kernel(const float* __restrict__ h3,
                                                   const int* __restrict__ batch,
                                                   float* __restrict__ g) {
    const int KRUN = 32;
    int c = threadIdx.x & 31;
    int grp = blockIdx.x * 8 + (threadIdx.x >> 5);
    int n0 = grp * KRUN;
    if (n0 >= N_NODES) return;
    int nend = n0 + KRUN;
    if (nend > N_NODES) nend = N_NODES;
    float acc = 0.f;
    int curb = -1;
    for (int nn = n0; nn < nend; ++nn) {
        int b = batch[nn];
        if (b != curb) {
            if (curb >= 0) atomicAdd(&g[curb * 32 + c], acc);
            acc = 0.f;
            curb = b;
        }
        acc += h3[(size_t)nn * 32 + c];
    }
    if (curb >= 0) atomicAdd(&g[curb * 32 + c], acc);
}

__global__ __launch_bounds__(256) void final_head(const float* __restrict__ g,
                                                  const float* __restrict__ Wfc1,
                                                  const float* __restrict__ bfc1,
                                                  const float* __restrict__ Wfc2,
                                                  const float* __restrict__ bfc2,
                                                  float* __restrict__ out) {
    __shared__ float sg[NGRAPH * 32];
    __shared__ float s1[NGRAPH * 32];
    const int t = threadIdx.x;
    for (int i = t; i < NGRAPH * 32; i += 256) sg[i] = g[i];
    __syncthreads();
    for (int i = t; i < NGRAPH * 32; i += 256) {
        int gi = i >> 5, c = i & 31;
        float acc = bfc1[c];
#pragma unroll
        for (int k = 0; k < 32; ++k) acc += sg[gi * 32 + k] * Wfc1[k * 32 + c];
        s1[i] = acc > 0.f ? acc : 0.f;
    }
    __syncthreads();
    if (t < NGRAPH * 2) {
        int gi = t >> 1, cls = t & 1;
        float acc = bfc2[cls];
#pragma unroll
        for (int k = 0; k < 32; ++k) acc += s1[gi * 32 + k] * Wfc2[k * 2 + cls];
        out[t] = 1.f / (1.f + expf(-acc));
    }
}

// ============================ launcher ============================
extern "C" void kernel_launch(void* const* d_in, const int* in_sizes, int n_in,
                              void* d_out, int out_size, void* d_ws, size_t ws_size,
                              hipStream_t stream) {
    const float* x       = (const float*)d_in[0];
    const int*   eraw    = (const int*)d_in[1];
    const int*   braw    = (const int*)d_in[2];
    const float* W1_rel  = (const float*)d_in[3];
    const float* b1_rel  = (const float*)d_in[4];
    const float* W1_root = (const float*)d_in[5];
    const float* Wg      = (const float*)d_in[6];
    const float* attS    = (const float*)d_in[7];
    const float* attD    = (const float*)d_in[8];
    const float* bg      = (const float*)d_in[9];
    const float* W5_rel  = (const float*)d_in[10];
    const float* b5_rel  = (const float*)d_in[11];
    const float* W5_root = (const float*)d_in[12];
    const float* Wfc1    = (const float*)d_in[13];
    const float* bfc1    = (const float*)d_in[14];
    const float* Wfc2    = (const float*)d_in[15];
    const float* bfc2    = (const float*)d_in[16];
    float* out = (float*)d_out;

    // workspace layout (~36.2 MB total)
    float* f     = (float*)d_ws;
    float* xrb   = f;                                // N*64
    float* h1    = xrb + (size_t)N_NODES * 64;       // N*32 (h1, then h3)
    float* asrc  = h1 + (size_t)N_NODES * 32;        // N*16
    float* adst  = asrc + (size_t)N_NODES * 16;      // N*16
    float* attc  = adst + (size_t)N_NODES * 16;      // 1024
    float* gpool = attc + 1024;                      // 2048
    int* esrcd   = (int*)(gpool + 2048);             // E
    int* edstd   = esrcd + N_EDGES;                  // E
    int* batchd  = edstd + N_EDGES;                  // N
    int* deg     = batchd + N_NODES;                 // N+1
    int* off     = deg + (N_NODES + 1);              // N+1
    int* cur     = off + (N_NODES + 1);              // N
    int* nbr     = cur + N_NODES;                    // E+N

    // ---- decode indices + CSR build ----
    decode_edges<<<(N_EDGES + 255) / 256, 256, 0, stream>>>(eraw, esrcd, edstd);
    decode_batch<<<(N_NODES + 255) / 256, 256, 0, stream>>>(braw, batchd);
    init_kernel<<<(N_NODES + 255) / 256, 256, 0, stream>>>(deg, gpool);
    hist_kernel<<<(N_EDGES + 255) / 256, 256, 0, stream>>>(edstd, deg);
    scan_kernel<<<1, 1024, 0, stream>>>(deg, off, cur);
    place_kernel<<<(N_EDGES + N_NODES + 255) / 256, 256, 0, stream>>>(esrcd, edstd, cur, nbr);

    // ---- stage 1: GraphConv(128 -> 32) ----
    node_linear2<<<(N_NODES + 7) / 8, 256, 0, stream>>>(x, W1_rel, W1_root, b1_rel, xrb, N_NODES);
    graphconv_gather<<<(N_NODES + 3) / 4, 256, 0, stream>>>(xrb, off, nbr, h1);

    // ---- stage 2: GATConv(32 -> 16x32) fused with stage-3 projections ----
    attc_kernel<<<1, 1024, 0, stream>>>(Wg, attS, attD, attc);
    gat_att<<<(N_NODES + 7) / 8, 256, 0, stream>>>(h1, attc, asrc, adst);
    gat_mega<<<N_NODES / 8, 512, 0, stream>>>(h1, asrc, adst, off, nbr, Wg, bg,
                                              W5_rel, W5_root, b5_rel, xrb);

    // ---- stage 3: GraphConv(512 -> 32) aggregation (projections already in xrb) ----
    graphconv_gather<<<(N_NODES + 3) / 4, 256, 0, stream>>>(xrb, off, nbr, h1);  // h3

    // ---- pool + MLP head ----
    pool_kernel<<<((N_NODES + 31) / 32 + 7) / 8, 256, 0, stream>>>(h1, batchd, gpool);
    final_head<<<1, 256, 0, stream>>>(gpool, Wfc1, bfc1, Wfc2, bfc2, out);
}

// Round 9
// 696.377 us; speedup vs baseline: 1.1783x; 1.1783x over previous
//
#include <hip/hip_runtime.h>
#include <stdint.h>

#define N_NODES 50000
#define N_EDGES 800000
#define NFEAT 128
#define DIM 32
#define HEADS 16
#define NGRAPH 64

__device__ inline int clampN(int v) {
    return v < 0 ? 0 : (v >= N_NODES ? N_NODES - 1 : v);
}

__device__ inline float lrelu(float e) { return e < 0.f ? 0.2f * e : e; }

// ============================ index decode (int32/int64 robust) ============================
__device__ inline bool edges_are_i64(const int* raw) {
    int acc = 0;
#pragma unroll
    for (int i = 1; i < 16; i += 2) acc |= raw[2 * N_EDGES - 16 + i];
    return acc == 0;   // random dst values: odd words all-zero only if int64
}

// decode + degree histogram fused (deg must be pre-initialized to 1)
__global__ __launch_bounds__(256) void decode_edges_hist(const int* __restrict__ raw,
                                                         int* __restrict__ esrc,
                                                         int* __restrict__ edst,
                                                         int* __restrict__ deg) {
    const bool is64 = edges_are_i64(raw);
    int e = blockIdx.x * 256 + threadIdx.x;
    if (e < N_EDGES) {
        int s, d;
        if (is64) { s = raw[2 * e]; d = raw[2 * (N_EDGES + e)]; }
        else      { s = raw[e];     d = raw[N_EDGES + e]; }
        s = clampN(s); d = clampN(d);
        esrc[e] = s; edst[e] = d;
        atomicAdd(&deg[d], 1);
    }
}

__global__ __launch_bounds__(256) void decode_batch(const int* __restrict__ raw,
                                                    int* __restrict__ out) {
    int acc = 0;
#pragma unroll
    for (int i = 1; i < 16; i += 2) acc |= raw[N_NODES - 16 + i];
    const bool is64 = (acc == 0);  // tail of batch is ~63 (nonzero) if int32
    int b = blockIdx.x * 256 + threadIdx.x;
    if (b < N_NODES) {
        int v = is64 ? raw[2 * b] : raw[b];
        out[b] = v < 0 ? 0 : (v >= NGRAPH ? NGRAPH - 1 : v);
    }
}

// ============================ CSR build ============================
__global__ __launch_bounds__(256) void init_kernel(int* __restrict__ deg, float* __restrict__ gpool) {
    int i = blockIdx.x * 256 + threadIdx.x;
    if (i < N_NODES) deg[i] = 1;          // self-loop for GAT
    if (i < NGRAPH * DIM) gpool[i] = 0.f;
}

__global__ __launch_bounds__(1024) void scan_kernel(const int* __restrict__ deg,
                                                    int* __restrict__ off, int* __restrict__ cur) {
    __shared__ int part[1024];
    const int t = threadIdx.x;
    const int CH = (N_NODES + 1023) / 1024;  // 49
    int b0 = t * CH, b1 = b0 + CH;
    if (b0 > N_NODES) b0 = N_NODES;
    if (b1 > N_NODES) b1 = N_NODES;
    int s = 0;
    for (int i = b0; i < b1; ++i) s += deg[i];
    part[t] = s;
    __syncthreads();
    for (int ofs = 1; ofs < 1024; ofs <<= 1) {
        int v = part[t];
        int u = (t >= ofs) ? part[t - ofs] : 0;
        __syncthreads();
        part[t] = v + u;
        __syncthreads();
    }
    int run = (t > 0) ? part[t - 1] : 0;
    for (int i = b0; i < b1; ++i) { off[i] = run; cur[i] = run; run += deg[i]; }
    if (t == 1023) off[N_NODES] = part[1023];
}

__global__ __launch_bounds__(256) void place_kernel(const int* __restrict__ esrc,
                                                    const int* __restrict__ edst,
                                                    int* __restrict__ cur, int* __restrict__ nbr) {
    int idx = blockIdx.x * 256 + threadIdx.x;
    if (idx >= N_EDGES + N_NODES) return;
    int d, v;
    if (idx < N_EDGES) { d = edst[idx]; v = esrc[idx]; }  // already clamped
    else { d = idx - N_EDGES; v = d; }
    int p = atomicAdd(&cur[d], 1);
    nbr[p] = v;
}

// ============================ stage-1 node GEMM: xrb = [x@W1_rel | x@W1_root + b1] ============================
__global__ __launch_bounds__(256) void node_linear2(const float* __restrict__ x,
                                                    const float* __restrict__ Wa,
                                                    const float* __restrict__ Wb,
                                                    const float* __restrict__ bias_b,
                                                    float* __restrict__ xrb, int n) {
    constexpr int KC = 128;
    constexpr int NB = 8;
    __shared__ float sWt[2][32][KC + 4];
    __shared__ float sX[NB][KC];
    const int t = threadIdx.x;
    const int o = t & 63;
    const int mat = o >> 5;
    const int c = o & 31;
    const int sub = t >> 6;
    const int base = blockIdx.x * NB;

    for (int i = t; i < 2 * KC * 32; i += 256) {
        int m = i >= KC * 32;
        int j = i - m * KC * 32;
        int kk = j >> 5, cc = j & 31;
        sWt[m][cc][kk] = (m ? Wb : Wa)[kk * 32 + cc];
    }
    for (int i = t; i < NB * KC; i += 256) {
        int r = i >> 7, kk = i & (KC - 1);
        int node = base + r;
        sX[r][kk] = (node < n) ? x[(size_t)node * KC + kk] : 0.f;
    }
    __syncthreads();
    float acc[2] = {0.f, 0.f};
#pragma unroll 4
    for (int kv = 0; kv < KC / 4; ++kv) {
        const float4 w = *(const float4*)&sWt[mat][c][kv * 4];
#pragma unroll
        for (int s = 0; s < 2; ++s) {
            const float4 xv = *(const float4*)&sX[sub + s * 4][kv * 4];
            acc[s] += w.x * xv.x + w.y * xv.y + w.z * xv.z + w.w * xv.w;
        }
    }
    const float bb = (mat == 1) ? bias_b[c] : 0.f;
#pragma unroll
    for (int s = 0; s < 2; ++s) {
        int node = base + sub + s * 4;
        if (node < n) xrb[(size_t)node * 64 + mat * 32 + c] = acc[s] + bb;
    }
}

// ============================ GraphConv gather (unrolled x4) ============================
__global__ __launch_bounds__(256) void graphconv_gather(const float* __restrict__ xrb,
                                                        const int* __restrict__ off,
                                                        const int* __restrict__ nbr,
                                                        float* __restrict__ out) {
    int d = blockIdx.x * 4 + (threadIdx.x >> 6);
    if (d >= N_NODES) return;
    const int l = threadIdx.x & 63;
    const int c = l & 31, half = l >> 5;
    const int j0 = off[d], j1 = off[d + 1];
    float acc = 0.f;
    int j = j0 + half;
    // 4 neighbors in flight per half (8 per wave)
    for (; j + 6 < j1; j += 8) {
        int s0 = nbr[j], s1 = nbr[j + 2], s2 = nbr[j + 4], s3 = nbr[j + 6];
        float v0 = xrb[(size_t)s0 * 64 + c];
        float v1 = xrb[(size_t)s1 * 64 + c];
        float v2 = xrb[(size_t)s2 * 64 + c];
        float v3 = xrb[(size_t)s3 * 64 + c];
        acc += (v0 + v1) + (v2 + v3);
    }
    for (; j < j1; j += 2) acc += xrb[(size_t)nbr[j] * 64 + c];
    acc += __shfl_xor(acc, 32);
    acc += xrb[(size_t)d * 64 + 32 + c] - xrb[(size_t)d * 64 + c];
    if (half == 0) out[(size_t)d * 32 + c] = acc > 0.f ? acc : 0.f;
}

// ============================ GAT attention composite vectors ============================
__global__ __launch_bounds__(1024) void attc_kernel(const float* __restrict__ Wg,
                                                    const float* __restrict__ attS,
                                                    const float* __restrict__ attD,
                                                    float* __restrict__ attc) {
    const int t = threadIdx.x;
    const int sd = t >> 9, k = (t >> 4) & 31, hd = t & 15;
    const float* att = sd ? attD : attS;
    float acc = 0.f;
#pragma unroll
    for (int c = 0; c < 32; ++c) acc += Wg[k * 512 + hd * 32 + c] * att[hd * 32 + c];
    attc[t] = acc;
}

__global__ __launch_bounds__(256) void gat_att(const float* __restrict__ h1,
                                               const float* __restrict__ attc,
                                               float* __restrict__ asrc,
                                               float* __restrict__ adst) {
    __shared__ float sh1[8][32];
    __shared__ float sattc[1024];
    const int t = threadIdx.x;
    for (int i = t; i < 1024; i += 256) sattc[i] = attc[i];
    {
        int n0 = t >> 5, k = t & 31;
        sh1[n0][k] = h1[(size_t)(blockIdx.x * 8 + n0) * 32 + k];
    }
    __syncthreads();
    const int nl = t >> 5, hd = (t >> 1) & 15, sd = t & 1;
    float acc = 0.f;
#pragma unroll
    for (int k = 0; k < 32; ++k) acc += sh1[nl][k] * sattc[sd * 512 + k * 16 + hd];
    (sd ? adst : asrc)[(size_t)(blockIdx.x * 8 + nl) * 16 + hd] = acc;
}

// ============================ SPLIT PATH: gather kernel (zero LDS, high occupancy) ============================
// wave per dst node; lane: hd = l>>2 (16 heads), kb = (l&3)*8 (4 dim-groups of 8)
// writes normalized per-head aggregate agg[d][hd*32 + dim] (offset 8*l -> contiguous)
__global__ __launch_bounds__(256) void gat_gather(const float* __restrict__ h1,
                                                  const float* __restrict__ asrc,
                                                  const float* __restrict__ adst,
                                                  const int* __restrict__ off,
                                                  const int* __restrict__ nbr,
                                                  float* __restrict__ agg) {
    const int d = blockIdx.x * 4 + (threadIdx.x >> 6);
    const int l = threadIdx.x & 63;
    const int hd = l >> 2;
    const int kb = (l & 3) << 3;
    const float adst_v = adst[(size_t)d * 16 + hd];
    const int j0 = off[d], j1 = off[d + 1];

    // pass 1: running max (unroll 4)
    float m = -1e30f;
    int j = j0;
    for (; j + 4 <= j1; j += 4) {
        int s0 = nbr[j], s1 = nbr[j + 1], s2 = nbr[j + 2], s3 = nbr[j + 3];
        float e0 = lrelu(asrc[(size_t)s0 * 16 + hd] + adst_v);
        float e1 = lrelu(asrc[(size_t)s1 * 16 + hd] + adst_v);
        float e2 = lrelu(asrc[(size_t)s2 * 16 + hd] + adst_v);
        float e3 = lrelu(asrc[(size_t)s3 * 16 + hd] + adst_v);
        m = fmaxf(m, fmaxf(fmaxf(e0, e1), fmaxf(e2, e3)));
    }
    for (; j < j1; ++j)
        m = fmaxf(m, lrelu(asrc[(size_t)nbr[j] * 16 + hd] + adst_v));

    // pass 2: exp + weighted accumulate (unroll 2)
    float den = 0.f;
    float a0x = 0.f, a0y = 0.f, a0z = 0.f, a0w = 0.f;
    float a1x = 0.f, a1y = 0.f, a1z = 0.f, a1w = 0.f;
    j = j0;
    for (; j + 2 <= j1; j += 2) {
        int s0 = nbr[j], s1 = nbr[j + 1];
        float e0 = lrelu(asrc[(size_t)s0 * 16 + hd] + adst_v);
        float e1 = lrelu(asrc[(size_t)s1 * 16 + hd] + adst_v);
        float ex0 = expf(e0 - m), ex1 = expf(e1 - m);
        den += ex0 + ex1;
        const float4 h00 = *(const float4*)&h1[(size_t)s0 * 32 + kb];
        const float4 h01 = *(const float4*)&h1[(size_t)s0 * 32 + kb + 4];
        const float4 h10 = *(const float4*)&h1[(size_t)s1 * 32 + kb];
        const float4 h11 = *(const float4*)&h1[(size_t)s1 * 32 + kb + 4];
        a0x += ex0 * h00.x + ex1 * h10.x; a0y += ex0 * h00.y + ex1 * h10.y;
        a0z += ex0 * h00.z + ex1 * h10.z; a0w += ex0 * h00.w + ex1 * h10.w;
        a1x += ex0 * h01.x + ex1 * h11.x; a1y += ex0 * h01.y + ex1 * h11.y;
        a1z += ex0 * h01.z + ex1 * h11.z; a1w += ex0 * h01.w + ex1 * h11.w;
    }
    if (j < j1) {
        int s0 = nbr[j];
        float e0 = lrelu(asrc[(size_t)s0 * 16 + hd] + adst_v);
        float ex0 = expf(e0 - m);
        den += ex0;
        const float4 h00 = *(const float4*)&h1[(size_t)s0 * 32 + kb];
        const float4 h01 = *(const float4*)&h1[(size_t)s0 * 32 + kb + 4];
        a0x += ex0 * h00.x; a0y += ex0 * h00.y; a0z += ex0 * h00.z; a0w += ex0 * h00.w;
        a1x += ex0 * h01.x; a1y += ex0 * h01.y; a1z += ex0 * h01.z; a1w += ex0 * h01.w;
    }
    const float r = 1.f / (den + 1e-16f);
    float* ap = agg + (size_t)d * 512 + 8 * l;
    float4 o0 = {a0x * r, a0y * r, a0z * r, a0w * r};
    float4 o1 = {a1x * r, a1y * r, a1z * r, a1w * r};
    *(float4*)ap = o0;
    *(float4*)(ap + 4) = o1;
}

// ============================ SPLIT PATH: FFN kernel (agg -> h2 -> xrb) ============================
__global__ __launch_bounds__(512) void gat_ffn(const float* __restrict__ agg,
                                               const float* __restrict__ Wg,
                                               const float* __restrict__ bg,
                                               const float* __restrict__ W5_rel,
                                               const float* __restrict__ W5_root,
                                               const float* __restrict__ b5,
                                               float* __restrict__ xrb) {
    __shared__ float sA[8][512];   // agg tile; later aliased as spart[8][8][64]
    __shared__ float sH[8][512];   // h2 tile
    const int t = threadIdx.x;
    const int base = blockIdx.x * 8;

    // stage agg tile (coalesced float4)
    {
        const float4* av = (const float4*)(agg + (size_t)base * 512);
        float4* sv = (float4*)&sA[0][0];
        sv[t] = av[t];
        sv[t + 512] = av[t + 512];
    }
    __syncthreads();

    // phase1: h2 = relu(agg @ Wg + bg)
    {
        const int hh = (t >> 5) << 5;
        float acc[8] = {0.f, 0.f, 0.f, 0.f, 0.f, 0.f, 0.f, 0.f};
        for (int k = 0; k < 32; ++k) {
            const float wv = Wg[k * 512 + t];
#pragma unroll
            for (int nl = 0; nl < 8; ++nl) acc[nl] += sA[nl][hh + k] * wv;
        }
        const float bgv = bg[t];
#pragma unroll
        for (int nl = 0; nl < 8; ++nl) {
            float v = acc[nl] + bgv;
            sH[nl][t] = v > 0.f ? v : 0.f;
        }
    }
    __syncthreads();   // sA reads complete block-wide -> safe to alias

    // phase2: partials over col range [w*64, w*64+64)
    float* spart = &sA[0][0];  // [ww*8 + nl][l] -> (ww*8+nl)*64 + l
    const int w = t >> 6, l = t & 63;
    {
        const float* wp = (l < 32) ? (W5_rel + l) : (W5_root + (l - 32));
        float p[8] = {0.f, 0.f, 0.f, 0.f, 0.f, 0.f, 0.f, 0.f};
        const int c0 = w * 64;
        for (int cc = 0; cc < 64; ++cc) {
            const int col = c0 + cc;
            const float wv = wp[(size_t)col * 32];
#pragma unroll
            for (int nl = 0; nl < 8; ++nl) p[nl] += sH[nl][col] * wv;
        }
#pragma unroll
        for (int nl = 0; nl < 8; ++nl) spart[(size_t)(w * 8 + nl) * 64 + l] = p[nl];
    }
    __syncthreads();

    // reduce: wave w finalizes node nl = w
    {
        float acc = (l >= 32) ? b5[l - 32] : 0.f;
#pragma unroll
        for (int ww = 0; ww < 8; ++ww) acc += spart[(size_t)(ww * 8 + w) * 64 + l];
        xrb[(size_t)(base + w) * 64 + l] = acc;
    }
}

// ============================ FALLBACK: fused GAT mega (32KB LDS, unrolled gather) ============================
__global__ __launch_bounds__(512) void gat_mega(const float* __restrict__ h1,
                                                const float* __restrict__ asrc,
                                                const float* __restrict__ adst,
                                                const int* __restrict__ off,
                                                const int* __restrict__ nbr,
                                                const float* __restrict__ Wg,
                                                const float* __restrict__ bg,
                                                const float* __restrict__ W5_rel,
                                                const float* __restrict__ W5_root,
                                                const float* __restrict__ b5,
                                                float* __restrict__ xrb) {
    __shared__ float sh_agg[8][512];   // aliased as spart in phase2
    __shared__ float sh_h2[8][512];
    const int t = threadIdx.x;
    const int w = t >> 6, l = t & 63;
    const int d = blockIdx.x * 8 + w;

    {
        const int hd = l >> 2;
        const int kb = (l & 3) << 3;
        const float adst_v = adst[(size_t)d * 16 + hd];
        const int j0 = off[d], j1 = off[d + 1];
        float m = -1e30f;
        int j = j0;
        for (; j + 4 <= j1; j += 4) {
            int s0 = nbr[j], s1 = nbr[j + 1], s2 = nbr[j + 2], s3 = nbr[j + 3];
            float e0 = lrelu(asrc[(size_t)s0 * 16 + hd] + adst_v);
            float e1 = lrelu(asrc[(size_t)s1 * 16 + hd] + adst_v);
            float e2 = lrelu(asrc[(size_t)s2 * 16 + hd] + adst_v);
            float e3 = lrelu(asrc[(size_t)s3 * 16 + hd] + adst_v);
            m = fmaxf(m, fmaxf(fmaxf(e0, e1), fmaxf(e2, e3)));
        }
        for (; j < j1; ++j)
            m = fmaxf(m, lrelu(asrc[(size_t)nbr[j] * 16 + hd] + adst_v));

        float den = 0.f;
        float a0x = 0.f, a0y = 0.f, a0z = 0.f, a0w = 0.f;
        float a1x = 0.f, a1y = 0.f, a1z = 0.f, a1w = 0.f;
        j = j0;
        for (; j + 2 <= j1; j += 2) {
            int s0 = nbr[j], s1 = nbr[j + 1];
            float e0 = lrelu(asrc[(size_t)s0 * 16 + hd] + adst_v);
            float e1 = lrelu(asrc[(size_t)s1 * 16 + hd] + adst_v);
            float ex0 = expf(e0 - m), ex1 = expf(e1 - m);
            den += ex0 + ex1;
            const float4 h00 = *(const float4*)&h1[(size_t)s0 * 32 + kb];
            const float4 h01 = *(const float4*)&h1[(size_t)s0 * 32 + kb + 4];
            const float4 h10 = *(const float4*)&h1[(size_t)s1 * 32 + kb];
            const float4 h11 = *(const float4*)&h1[(size_t)s1 * 32 + kb + 4];
            a0x += ex0 * h00.x + ex1 * h10.x; a0y += ex0 * h00.y + ex1 * h10.y;
            a0z += ex0 * h00.z + ex1 * h10.z; a0w += ex0 * h00.w + ex1 * h10.w;
            a1x += ex0 * h01.x + ex1 * h11.x; a1y += ex0 * h01.y + ex1 * h11.y;
            a1z += ex0 * h01.z + ex1 * h11.z; a1w += ex0 * h01.w + ex1 * h11.w;
        }
        if (j < j1) {
            int s0 = nbr[j];
            float e0 = lrelu(asrc[(size_t)s0 * 16 + hd] + adst_v);
            float ex0 = expf(e0 - m);
            den += ex0;
            const float4 h00 = *(const float4*)&h1[(size_t)s0 * 32 + kb];
            const float4 h01 = *(const float4*)&h1[(size_t)s0 * 32 + kb + 4];
            a0x += ex0 * h00.x; a0y += ex0 * h00.y; a0z += ex0 * h00.z; a0w += ex0 * h00.w;
            a1x += ex0 * h01.x; a1y += ex0 * h01.y; a1z += ex0 * h01.z; a1w += ex0 * h01.w;
        }
        const float r = 1.f / (den + 1e-16f);
        float* ap = &sh_agg[w][8 * l];
        ap[0] = a0x * r; ap[1] = a0y * r; ap[2] = a0z * r; ap[3] = a0w * r;
        ap[4] = a1x * r; ap[5] = a1y * r; ap[6] = a1z * r; ap[7] = a1w * r;
    }
    __syncthreads();

    {
        const int hh = (t >> 5) << 5;
        float acc[8] = {0.f, 0.f, 0.f, 0.f, 0.f, 0.f, 0.f, 0.f};
        for (int k = 0; k < 32; ++k) {
            const float wv = Wg[k * 512 + t];
#pragma unroll
            for (int nl = 0; nl < 8; ++nl) acc[nl] += sh_agg[nl][hh + k] * wv;
        }
        const float bgv = bg[t];
#pragma unroll
        for (int nl = 0; nl < 8; ++nl) {
            float v = acc[nl] + bgv;
            sh_h2[nl][t] = v > 0.f ? v : 0.f;
        }
    }
    __syncthreads();

    float* spart = &sh_agg[0][0];
    {
        const float* wp = (l < 32) ? (W5_rel + l) : (W5_root + (l - 32));
        float p[8] = {0.f, 0.f, 0.f, 0.f, 0.f, 0.f, 0.f, 0.f};
        const int c0 = w * 64;
        for (int cc = 0; cc < 64; ++cc) {
            const int col = c0 + cc;
            const float wv = wp[(size_t)col * 32];
#pragma unroll
            for (int nl = 0; nl < 8; ++nl) p[nl] += sh_h2[nl][col] * wv;
        }
#pragma unroll
        for (int nl = 0; nl < 8; ++nl) spart[(size_t)(w * 8 + nl) * 64 + l] = p[nl];
    }
    __syncthreads();

    {
        float acc = (l >= 32) ? b5[l - 32] : 0.f;
#pragma unroll
        for (int ww = 0; ww < 8; ++ww) acc += spart[(size_t)(ww * 8 + w) * 64 + l];
        xrb[(size_t)(blockIdx.x * 8 + w) * 64 + l] = acc;
    }
}

// ============================ pool + head ============================
__global__ __launch_bounds__(256) void pool_kernel(const float* __restrict__ h3,
                                                   const int* __restrict__ batch,
                                                   float* __restrict__ g) {
    const int KRUN = 32;
    int c = threadIdx.x & 31;
    int grp = blockIdx.x * 8 + (threadIdx.x >> 5);
    int n0 = grp * KRUN;
    if (n0 >= N_NODES) return;
    int nend = n0 + KRUN;
    if (nend > N_NODES) nend = N_NODES;
    float acc = 0.f;
    int curb = -1;
    for (int nn = n0; nn < nend; ++nn) {
        int b = batch[nn];
        if (b != curb) {
            if (curb >= 0) atomicAdd(&g[curb * 32 + c], acc);
            acc = 0.f;
            curb = b;
        }
        acc += h3[(size_t)nn * 32 + c];
    }
    if (curb >= 0) atomicAdd(&g[curb * 32 + c], acc);
}

__global__ __launch_bounds__(256) void final_head(const float* __restrict__ g,
                                                  const float* __restrict__ Wfc1,
                                                  const float* __restrict__ bfc1,
                                                  const float* __restrict__ Wfc2,
                                                  const float* __restrict__ bfc2,
                                                  float* __restrict__ out) {
    __shared__ float sg[NGRAPH * 32];
    __shared__ float s1[NGRAPH * 32];
    const int t = threadIdx.x;
    for (int i = t; i < NGRAPH * 32; i += 256) sg[i] = g[i];
    __syncthreads();
    for (int i = t; i < NGRAPH * 32; i += 256) {
        int gi = i >> 5, c = i & 31;
        float acc = bfc1[c];
#pragma unroll
        for (int k = 0; k < 32; ++k) acc += sg[gi * 32 + k] * Wfc1[k * 32 + c];
        s1[i] = acc > 0.f ? acc : 0.f;
    }
    __syncthreads();
    if (t < NGRAPH * 2) {
        int gi = t >> 1, cls = t & 1;
        float acc = bfc2[cls];
#pragma unroll
        for (int k = 0; k < 32; ++k) acc += s1[gi * 32 + k] * Wfc2[k * 2 + cls];
        out[t] = 1.f / (1.f + expf(-acc));
    }
}

// ============================ launcher ============================
extern "C" void kernel_launch(void* const* d_in, const int* in_sizes, int n_in,
                              void* d_out, int out_size, void* d_ws, size_t ws_size,
                              hipStream_t stream) {
    const float* x       = (const float*)d_in[0];
    const int*   eraw    = (const int*)d_in[1];
    const int*   braw    = (const int*)d_in[2];
    const float* W1_rel  = (const float*)d_in[3];
    const float* b1_rel  = (const float*)d_in[4];
    const float* W1_root = (const float*)d_in[5];
    const float* Wg      = (const float*)d_in[6];
    const float* attS    = (const float*)d_in[7];
    const float* attD    = (const float*)d_in[8];
    const float* bg      = (const float*)d_in[9];
    const float* W5_rel  = (const float*)d_in[10];
    const float* b5_rel  = (const float*)d_in[11];
    const float* W5_root = (const float*)d_in[12];
    const float* Wfc1    = (const float*)d_in[13];
    const float* bfc1    = (const float*)d_in[14];
    const float* Wfc2    = (const float*)d_in[15];
    const float* bfc2    = (const float*)d_in[16];
    float* out = (float*)d_out;

    // workspace layout (base ~39.4 MB; + optional 102.4 MB agg appended)
    float* f     = (float*)d_ws;
    float* xrb   = f;                                // N*64
    float* h1    = xrb + (size_t)N_NODES * 64;       // N*32 (h1, then h3)
    float* asrc  = h1 + (size_t)N_NODES * 32;        // N*16
    float* adst  = asrc + (size_t)N_NODES * 16;      // N*16
    float* attc  = adst + (size_t)N_NODES * 16;      // 1024
    float* gpool = attc + 1024;                      // 2048
    int* esrcd   = (int*)(gpool + 2048);             // E
    int* edstd   = esrcd + N_EDGES;                  // E
    int* batchd  = edstd + N_EDGES;                  // N
    int* deg     = batchd + N_NODES;                 // N+1
    int* off     = deg + (N_NODES + 1);              // N+1
    int* cur     = off + (N_NODES + 1);              // N
    int* nbr     = cur + N_NODES;                    // E+N
    // agg (split path only), 16B-aligned
    uintptr_t aggp = (uintptr_t)(nbr + (N_EDGES + N_NODES));
    aggp = (aggp + 15) & ~(uintptr_t)15;
    float* agg = (float*)aggp;
    const size_t need_split = (aggp - (uintptr_t)d_ws) + (size_t)N_NODES * 512 * 4;
    const bool use_split = ws_size >= need_split;

    // ---- decode + CSR build ----
    init_kernel<<<(N_NODES + 255) / 256, 256, 0, stream>>>(deg, gpool);
    decode_edges_hist<<<(N_EDGES + 255) / 256, 256, 0, stream>>>(eraw, esrcd, edstd, deg);
    decode_batch<<<(N_NODES + 255) / 256, 256, 0, stream>>>(braw, batchd);
    scan_kernel<<<1, 1024, 0, stream>>>(deg, off, cur);
    place_kernel<<<(N_EDGES + N_NODES + 255) / 256, 256, 0, stream>>>(esrcd, edstd, cur, nbr);

    // ---- stage 1: GraphConv(128 -> 32) ----
    node_linear2<<<(N_NODES + 7) / 8, 256, 0, stream>>>(x, W1_rel, W1_root, b1_rel, xrb, N_NODES);
    graphconv_gather<<<(N_NODES + 3) / 4, 256, 0, stream>>>(xrb, off, nbr, h1);

    // ---- stage 2: GATConv + stage-3 projections ----
    attc_kernel<<<1, 1024, 0, stream>>>(Wg, attS, attD, attc);
    gat_att<<<(N_NODES + 7) / 8, 256, 0, stream>>>(h1, attc, asrc, adst);
    if (use_split) {
        gat_gather<<<(N_NODES + 3) / 4, 256, 0, stream>>>(h1, asrc, adst, off, nbr, agg);
        gat_ffn<<<N_NODES / 8, 512, 0, stream>>>(agg, Wg, bg, W5_rel, W5_root, b5_rel, xrb);
    } else {
        gat_mega<<<N_NODES / 8, 512, 0, stream>>>(h1, asrc, adst, off, nbr, Wg, bg,
                                                  W5_rel, W5_root, b5_rel, xrb);
    }

    // ---- stage 3: GraphConv(512 -> 32) aggregation ----
    graphconv_gather<<<(N_NODES + 3) / 4, 256, 0, stream>>>(xrb, off, nbr, h1);  // h3

    // ---- pool + MLP head ----
    pool_kernel<<<((N_NODES + 31) / 32 + 7) / 8, 256, 0, stream>>>(h1, batchd, gpool);
    final_head<<<1, 256, 0, stream>>>(gpool, Wfc1, bfc1, Wfc2, bfc2, out);
}